// Round 12
// baseline (240.299 us; speedup 1.0000x reference)
//
#include <hip/hip_runtime.h>
#include <hip/hip_bf16.h>

typedef __attribute__((ext_vector_type(8))) short bf16x8;
typedef __attribute__((ext_vector_type(4))) float f32x4;

__device__ __forceinline__ float sigm(float x) {
    return __builtin_amdgcn_rcpf(1.0f + __expf(-x));
}
__device__ __forceinline__ float tanh_(float x) {
    float e = __expf(2.0f * x);
    return 1.0f - 2.0f * __builtin_amdgcn_rcpf(e + 1.0f);
}
__device__ __forceinline__ ushort f2bf(float f) {   // RNE float->bf16
    uint u = __float_as_uint(f);
    u = u + 0x7FFFu + ((u >> 16) & 1u);
    return (ushort)(u >> 16);
}
__device__ __forceinline__ float bf2f(ushort s) { return __uint_as_float(((uint)s) << 16); }

// ============ K1: e1 LSTM via MFMA, swapped operands, 16 waves x 1 tile (R10, frozen) ============
__global__ __launch_bounds__(1024) __attribute__((amdgpu_waves_per_eu(4, 4)))
void k1_enc(
    const float* __restrict__ x,
    const float* __restrict__ e1_Wih, const float* __restrict__ e1_Whh, const float* __restrict__ e1_b,
    const float* __restrict__ e2_Wih, const float* __restrict__ e2_b,
    const float* __restrict__ e2_Whh,
    float* __restrict__ dec_in)   // [ts][4096]
{
    __shared__ float x_s[16 * 772];
    __shared__ __align__(16) ushort h_hi[2][8][16][8];
    __shared__ __align__(16) ushort h_lo[2][8][16][8];
    __shared__ __align__(16) ushort x2_s[2][4][16][8];
    __shared__ __align__(16) float pe2_s[96 * 64];

    const int t = threadIdx.x;
    const int bBase = blockIdx.x * 16;
    const int wv = t >> 6, l = t & 63;
    const int row = l & 15, sub = l >> 4;

    for (int bb = 0; bb < 16; ++bb)
        for (int i = t; i < 768; i += 1024)
            x_s[bb * 772 + i] = x[(size_t)(bBase + bb) * 768 + i];

    auto loadW = [&](const float* rowbase, int k0, bool valid, bf16x8& hi8, bf16x8& lo8) {
        float f[8];
        if (valid) {
            float4 v0 = ((const float4*)(rowbase + k0))[0];
            float4 v1 = ((const float4*)(rowbase + k0))[1];
            f[0]=v0.x; f[1]=v0.y; f[2]=v0.z; f[3]=v0.w;
            f[4]=v1.x; f[5]=v1.y; f[6]=v1.z; f[7]=v1.w;
        } else {
            #pragma unroll
            for (int j = 0; j < 8; ++j) f[j] = 0.f;
        }
        #pragma unroll
        for (int j = 0; j < 8; ++j) {
            ushort h = f2bf(f[j]);
            hi8[j] = (short)h;
            lo8[j] = (short)f2bf(f[j] - bf2f(h));
        }
    };
    auto loadA = [&](int T, bool isE2, bf16x8& Ah0, bf16x8& Ah1, bf16x8& Al0, bf16x8& Al1, bf16x8& A2) {
        const int gate = row & 3, uq = row >> 2;
        const bool valid = !isE2 || (uq == 0);
        const int wr = isE2 ? gate : gate * 64 + T * 4 + uq;
        const float* rp = isE2 ? (e2_Wih + (size_t)wr * 64) : (e1_Whh + (size_t)wr * 64);
        loadW(rp, sub * 8,      valid, Ah0, Al0);
        loadW(rp, 32 + sub * 8, valid, Ah1, Al1);
        #pragma unroll
        for (int j = 0; j < 8; ++j) A2[j] = 0;
        if (valid) {
            if (!isE2) {
                if (sub < 3) {
                    const float* wihr = e1_Wih + (size_t)wr * 8;
                    #pragma unroll
                    for (int j = 0; j < 8; ++j) {
                        float f = wihr[j];
                        ushort hh = f2bf(f);
                        A2[j] = (sub < 2) ? (short)hh : (short)f2bf(f - bf2f(hh));
                    }
                } else {
                    float bb = e1_b[wr];
                    ushort hh = f2bf(bb);
                    A2[0] = (short)hh; A2[1] = (short)f2bf(bb - bf2f(hh));
                }
            } else if (sub == 3) {
                float bb = e2_b[wr];
                ushort hh = f2bf(bb);
                A2[0] = (short)hh; A2[1] = (short)f2bf(bb - bf2f(hh));
            }
        }
    };

    bf16x8 A0h0, A0h1, A0l0, A0l1, A0x;
    bf16x8 A2h0, A2h1, A2l0, A2l1, A2x;
    loadA(wv, false, A0h0, A0h1, A0l0, A0l1, A0x);
    if (wv == 15) loadA(0, true, A2h0, A2h1, A2l0, A2l1, A2x);

    __syncthreads();

    if (t < 1024) { ((ushort*)h_hi[0])[t] = 0; ((ushort*)h_lo[0])[t] = 0; }
    if (t < 384) {
        int sb = t >> 7, b = (t >> 3) & 15, j = t & 7;
        float xv = x_s[b * 772 + j];
        ushort hi = f2bf(xv);
        x2_s[0][sb][b][j] = (sb == 1) ? f2bf(xv - bf2f(hi)) : hi;
        x2_s[1][sb][b][j] = 0;
    } else if (t < 512) {
        int b = (t >> 3) & 15, j = t & 7;
        ushort v = (j < 2) ? (ushort)0x3F80 : (ushort)0;
        x2_s[0][3][b][j] = v;
        x2_s[1][3][b][j] = v;
    }

    const int cb = l & 15;
    const int u0_ = wv * 4 + sub;
    float c0r = 0.f;
    __syncthreads();

    #pragma unroll 1
    for (int ts = 0; ts < 96; ++ts) {
        const int p = ts & 1, pn = p ^ 1;

        bf16x8 Bh0 = *(const bf16x8*)&h_hi[p][sub][cb][0];
        bf16x8 Bh1 = *(const bf16x8*)&h_hi[p][4 + sub][cb][0];
        bf16x8 Bl0 = *(const bf16x8*)&h_lo[p][sub][cb][0];
        bf16x8 Bl1 = *(const bf16x8*)&h_lo[p][4 + sub][cb][0];
        bf16x8 Bx  = *(const bf16x8*)&x2_s[p][sub][cb][0];

        f32x4 u0 = {0.f,0.f,0.f,0.f}, v0 = {0.f,0.f,0.f,0.f};
        u0 = __builtin_amdgcn_mfma_f32_16x16x32_bf16(A0h0, Bh0, u0, 0, 0, 0);
        u0 = __builtin_amdgcn_mfma_f32_16x16x32_bf16(A0l0, Bh0, u0, 0, 0, 0);
        u0 = __builtin_amdgcn_mfma_f32_16x16x32_bf16(A0h0, Bl0, u0, 0, 0, 0);
        v0 = __builtin_amdgcn_mfma_f32_16x16x32_bf16(A0h1, Bh1, v0, 0, 0, 0);
        v0 = __builtin_amdgcn_mfma_f32_16x16x32_bf16(A0l1, Bh1, v0, 0, 0, 0);
        v0 = __builtin_amdgcn_mfma_f32_16x16x32_bf16(A0h1, Bl1, v0, 0, 0, 0);
        v0 = __builtin_amdgcn_mfma_f32_16x16x32_bf16(A0x,  Bx,  v0, 0, 0, 0);

        if (wv == 15) {
            f32x4 u2 = {0.f,0.f,0.f,0.f}, v2 = {0.f,0.f,0.f,0.f};
            u2 = __builtin_amdgcn_mfma_f32_16x16x32_bf16(A2h0, Bh0, u2, 0, 0, 0);
            u2 = __builtin_amdgcn_mfma_f32_16x16x32_bf16(A2l0, Bh0, u2, 0, 0, 0);
            u2 = __builtin_amdgcn_mfma_f32_16x16x32_bf16(A2h0, Bl0, u2, 0, 0, 0);
            v2 = __builtin_amdgcn_mfma_f32_16x16x32_bf16(A2h1, Bh1, v2, 0, 0, 0);
            v2 = __builtin_amdgcn_mfma_f32_16x16x32_bf16(A2l1, Bh1, v2, 0, 0, 0);
            v2 = __builtin_amdgcn_mfma_f32_16x16x32_bf16(A2h1, Bl1, v2, 0, 0, 0);
            v2 = __builtin_amdgcn_mfma_f32_16x16x32_bf16(A2x,  Bx,  v2, 0, 0, 0);
            if (ts > 0 && sub == 0) {
                f32x4 acc2 = u2 + v2;
                #pragma unroll
                for (int i = 0; i < 4; ++i)
                    pe2_s[(ts - 1) * 64 + i * 16 + cb] = acc2[i];
            }
        }

        {
            f32x4 acc = u0 + v0;
            c0r = fmaf(sigm(acc[1]), c0r, sigm(acc[0]) * tanh_(acc[2]));
            float hv = sigm(acc[3]) * tanh_(c0r);
            ushort hh = f2bf(hv);
            h_hi[pn][u0_ >> 3][cb][u0_ & 7] = hh;
            h_lo[pn][u0_ >> 3][cb][u0_ & 7] = f2bf(hv - bf2f(hh));
        }

        if (ts < 95 && t < 384) {
            int sb = t >> 7, b = (t >> 3) & 15, j = t & 7;
            float xv = x_s[b * 772 + (ts + 1) * 8 + j];
            ushort hi = f2bf(xv);
            x2_s[pn][sb][b][j] = (sb == 1) ? f2bf(xv - bf2f(hi)) : hi;
        }
        __syncthreads();
    }

    if (wv == 15) {
        bf16x8 Bh0 = *(const bf16x8*)&h_hi[0][sub][cb][0];
        bf16x8 Bh1 = *(const bf16x8*)&h_hi[0][4 + sub][cb][0];
        bf16x8 Bl0 = *(const bf16x8*)&h_lo[0][sub][cb][0];
        bf16x8 Bl1 = *(const bf16x8*)&h_lo[0][4 + sub][cb][0];
        bf16x8 Bx  = *(const bf16x8*)&x2_s[0][sub][cb][0];
        f32x4 u2 = {0.f,0.f,0.f,0.f}, v2 = {0.f,0.f,0.f,0.f};
        u2 = __builtin_amdgcn_mfma_f32_16x16x32_bf16(A2h0, Bh0, u2, 0, 0, 0);
        u2 = __builtin_amdgcn_mfma_f32_16x16x32_bf16(A2l0, Bh0, u2, 0, 0, 0);
        u2 = __builtin_amdgcn_mfma_f32_16x16x32_bf16(A2h0, Bl0, u2, 0, 0, 0);
        v2 = __builtin_amdgcn_mfma_f32_16x16x32_bf16(A2h1, Bh1, v2, 0, 0, 0);
        v2 = __builtin_amdgcn_mfma_f32_16x16x32_bf16(A2l1, Bh1, v2, 0, 0, 0);
        v2 = __builtin_amdgcn_mfma_f32_16x16x32_bf16(A2h1, Bl1, v2, 0, 0, 0);
        v2 = __builtin_amdgcn_mfma_f32_16x16x32_bf16(A2x,  Bx,  v2, 0, 0, 0);
        if (sub == 0) {
            f32x4 acc2 = u2 + v2;
            #pragma unroll
            for (int i = 0; i < 4; ++i)
                pe2_s[95 * 64 + i * 16 + cb] = acc2[i];
        }
    }
    __syncthreads();

    if (wv == 0 && l < 16) {
        const float w0 = e2_Whh[0], w1 = e2_Whh[1], w2 = e2_Whh[2], w3 = e2_Whh[3];
        float ni = pe2_s[l], nf = pe2_s[16 + l], ng = pe2_s[32 + l], no = pe2_s[48 + l];
        float h = 0.f, c = 0.f;
        #pragma unroll 1
        for (int ts = 0; ts < 96; ++ts) {
            float gi = ni, gf = nf, gg2 = ng, go = no;
            if (ts < 95) {
                int b2 = (ts + 1) * 64;
                ni = pe2_s[b2 + l]; nf = pe2_s[b2 + 16 + l];
                ng = pe2_s[b2 + 32 + l]; no = pe2_s[b2 + 48 + l];
            }
            gi = fmaf(h, w0, gi);
            gf = fmaf(h, w1, gf);
            gg2 = fmaf(h, w2, gg2);
            go = fmaf(h, w3, go);
            c = fmaf(sigm(gf), c, sigm(gi) * tanh_(gg2));
            h = sigm(go) * tanh_(c);
            dec_in[(size_t)ts * 4096 + bBase + l] = fmaxf(h, 0.f);
        }
    }
    if (wv >= 1 && wv <= 8) {
        int i = (wv - 1) * 64 + l;
        int B = i >> 5, j = i & 31;
        dec_in[(size_t)(96 + j) * 4096 + bBase + B] = x_s[B * 772 + (64 + j) * 8];
    }
}

// ============ K3 v2: decoder via MFMA, ONE WAVE = 2 BATCHES, zero barriers in time loop ============
// 512 threads (8 independent waves), grid 256 -> 2 waves/SIMD, no lockstep.
// d1 (K=16): K=32 chunk packs h_hi(k0-15)|h_lo(k16-31) -> 2 MFMAs/tile:
//   A1 = [Whh_hi | Whh_hi]  x  B1 = [h_hi | h_lo]
//   A2 = [Whh_lo | xslots]  x  B2 = [h_hi | xb],  xb = {x_hi,x_lo,1,1,x_hi,0,0,0},
//     xslots = {wih_hi, wih_hi, b_hi, b_lo, wih_lo, 0,0,0}  (x*wih hi/lo + bias).
// Tiles T=0..3: tile-row r -> (gate r&3, unit 4*(r>>2)+T) so lane (cb=l&15, sub=l>>4)
// gets acc[0..3] = i,f,g,o of (batch cb, unit 4*sub+T) — cells direct from C (R10
// validated mapping), lane's 4 units contiguous -> h written as one b64 hi + b64 lo.
// Tile 4 = fused d2-xg (rows 0-3); uses h entering the step -> pd2[ts-1]; post-loop
// pair for pd2[127]. d2 recurrence (2 lanes, depth-4 prefetch) + fc1 + fc2 wave-local.
__global__ __launch_bounds__(512) __attribute__((amdgpu_waves_per_eu(2, 2)))
void k3_dec(
    const float* __restrict__ dec_in,
    const float* __restrict__ d1_Wih, const float* __restrict__ d1_Whh, const float* __restrict__ d1_b,
    const float* __restrict__ d2_Wih, const float* __restrict__ d2_b,
    const float* __restrict__ d2_Whh,
    const float* __restrict__ fc1_W, const float* __restrict__ fc1_b,
    const float* __restrict__ fc2_W, const float* __restrict__ fc2_b,
    float* __restrict__ out)
{
    __shared__ float din_s[16][132];                    // 8.25 KB (pad 132: conflict-free staging)
    __shared__ __align__(16) ushort h_s[8][2][32];      // per wave x batch: hi[0-15] | lo[16-31]
    __shared__ __align__(16) float pd2_s[8][2][128][4]; // 32 KB
    __shared__ float d2h_s[8][2][128];                  // 8 KB
    __shared__ float mid_s[8][2][32];                   // 2 KB

    const int t = threadIdx.x;
    const int wb = t >> 6, l = t & 63;
    const int cb = l & 15, sub = l >> 4;
    const size_t bBase = (size_t)blockIdx.x * 16;

    // stage dec_in [ts][4096] -> din_s[local b][ts]
    for (int i = t; i < 2048; i += 512) {
        int ts = i >> 4, bb = i & 15;
        din_s[bb][ts] = dec_in[(size_t)ts * 4096 + bBase + bb];
    }

    // ---- A fragments (loop-invariant, VGPR-resident) ----
    bf16x8 A1t[5], A2t[5];
    {
        const int r = l & 15, g = r & 3, ul = r >> 2;
        #pragma unroll
        for (int T = 0; T < 4; ++T) {
            const int grow = g * 16 + 4 * ul + T;
            const float* wr = d1_Whh + grow * 16;
            float wih = d1_Wih[grow], bb = d1_b[grow];
            ushort wih_hi = f2bf(wih), wih_lo = f2bf(wih - bf2f(wih_hi));
            ushort b_hi = f2bf(bb),  b_lo  = f2bf(bb - bf2f(b_hi));
            bf16x8 a1, a2;
            #pragma unroll
            for (int j = 0; j < 8; ++j) {
                int k = sub * 8 + j;
                float w = wr[k & 15];
                ushort whi = f2bf(w);
                a1[j] = (short)whi;
                if (k < 16) a2[j] = (short)f2bf(w - bf2f(whi));
                else {
                    int kk = k - 16;
                    ushort v = (kk == 0) ? wih_hi : (kk == 1) ? wih_hi :
                               (kk == 2) ? b_hi   : (kk == 3) ? b_lo   :
                               (kk == 4) ? wih_lo : (ushort)0;
                    a2[j] = (short)v;
                }
            }
            A1t[T] = a1; A2t[T] = a2;
        }
        {   // d2 tile (rows 0-3 = d2 gates)
            const bool valid = r < 4;
            const float* wr = d2_Wih + (size_t)(r & 3) * 16;
            float bb2 = valid ? d2_b[r & 3] : 0.f;
            ushort b_hi = f2bf(bb2), b_lo = f2bf(bb2 - bf2f(b_hi));
            bf16x8 a1, a2;
            #pragma unroll
            for (int j = 0; j < 8; ++j) {
                int k = sub * 8 + j;
                float w = valid ? wr[k & 15] : 0.f;
                ushort whi = f2bf(w);
                a1[j] = (short)whi;
                if (k < 16) a2[j] = (short)f2bf(w - bf2f(whi));
                else {
                    int kk = k - 16;
                    ushort v = (kk == 2) ? b_hi : (kk == 3) ? b_lo : (ushort)0;
                    a2[j] = valid ? (short)v : (short)0;
                }
            }
            A1t[4] = a1; A2t[4] = a2;
        }
    }

    // init h = 0 (wave-local)
    if (l < 64) h_s[wb][l >> 5][l & 31] = 0;

    bf16x8 zero8;
    #pragma unroll
    for (int j = 0; j < 8; ++j) zero8[j] = 0;

    float c_st[4] = {0.f, 0.f, 0.f, 0.f};
    const int drow = 2 * wb + (cb & 1);
    __syncthreads();   // din_s staged by other waves

    // ================= d1 + fused d2-xg: 128 steps, NO barriers =================
    #pragma unroll 1
    for (int ts = 0; ts < 128; ++ts) {
        bf16x8 B1 = *(const bf16x8*)&h_s[wb][cb & 1][sub * 8];
        float xv = din_s[drow][ts];
        ushort xhi = f2bf(xv), xlo = f2bf(xv - bf2f(xhi));
        bf16x8 xb = zero8;
        xb[0] = (short)xhi; xb[1] = (short)xlo;
        xb[2] = (short)0x3F80; xb[3] = (short)0x3F80; xb[4] = (short)xhi;
        bf16x8 B2 = (sub < 2) ? B1 : (sub == 2) ? xb : zero8;

        f32x4 z = {0.f, 0.f, 0.f, 0.f};
        f32x4 a0 = __builtin_amdgcn_mfma_f32_16x16x32_bf16(A1t[0], B1, z, 0, 0, 0);
        a0 = __builtin_amdgcn_mfma_f32_16x16x32_bf16(A2t[0], B2, a0, 0, 0, 0);
        f32x4 a1 = __builtin_amdgcn_mfma_f32_16x16x32_bf16(A1t[1], B1, z, 0, 0, 0);
        a1 = __builtin_amdgcn_mfma_f32_16x16x32_bf16(A2t[1], B2, a1, 0, 0, 0);
        f32x4 a2 = __builtin_amdgcn_mfma_f32_16x16x32_bf16(A1t[2], B1, z, 0, 0, 0);
        a2 = __builtin_amdgcn_mfma_f32_16x16x32_bf16(A2t[2], B2, a2, 0, 0, 0);
        f32x4 a3 = __builtin_amdgcn_mfma_f32_16x16x32_bf16(A1t[3], B1, z, 0, 0, 0);
        a3 = __builtin_amdgcn_mfma_f32_16x16x32_bf16(A2t[3], B2, a3, 0, 0, 0);
        f32x4 a4 = __builtin_amdgcn_mfma_f32_16x16x32_bf16(A1t[4], B1, z, 0, 0, 0);
        a4 = __builtin_amdgcn_mfma_f32_16x16x32_bf16(A2t[4], B2, a4, 0, 0, 0);

        if (ts > 0 && sub == 0 && cb < 2)   // d2-xg from h entering this step
            *(float4*)&pd2_s[wb][cb][ts - 1][0] = make_float4(a4[0], a4[1], a4[2], a4[3]);

        float hn[4];
        {
            c_st[0] = fmaf(sigm(a0[1]), c_st[0], sigm(a0[0]) * tanh_(a0[2]));
            hn[0] = sigm(a0[3]) * tanh_(c_st[0]);
            c_st[1] = fmaf(sigm(a1[1]), c_st[1], sigm(a1[0]) * tanh_(a1[2]));
            hn[1] = sigm(a1[3]) * tanh_(c_st[1]);
            c_st[2] = fmaf(sigm(a2[1]), c_st[2], sigm(a2[0]) * tanh_(a2[2]));
            hn[2] = sigm(a2[3]) * tanh_(c_st[2]);
            c_st[3] = fmaf(sigm(a3[1]), c_st[3], sigm(a3[0]) * tanh_(a3[2]));
            hn[3] = sigm(a3[3]) * tanh_(c_st[3]);
        }
        if (cb < 2) {   // lane's units are 4*sub+T, T=0..3 (contiguous)
            uint2 phi, plo;
            phi.x = (uint)f2bf(hn[0]) | ((uint)f2bf(hn[1]) << 16);
            phi.y = (uint)f2bf(hn[2]) | ((uint)f2bf(hn[3]) << 16);
            plo.x = (uint)f2bf(hn[0] - bf2f(f2bf(hn[0]))) | ((uint)f2bf(hn[1] - bf2f(f2bf(hn[1]))) << 16);
            plo.y = (uint)f2bf(hn[2] - bf2f(f2bf(hn[2]))) | ((uint)f2bf(hn[3] - bf2f(f2bf(hn[3]))) << 16);
            *(uint2*)&h_s[wb][cb][4 * sub] = phi;
            *(uint2*)&h_s[wb][cb][16 + 4 * sub] = plo;
        }
    }

    // ---- pd2[127] from final h ----
    {
        bf16x8 B1f = *(const bf16x8*)&h_s[wb][cb & 1][sub * 8];
        bf16x8 onev = zero8; onev[2] = (short)0x3F80; onev[3] = (short)0x3F80;
        bf16x8 B2f = (sub < 2) ? B1f : (sub == 2) ? onev : zero8;
        f32x4 z = {0.f, 0.f, 0.f, 0.f};
        f32x4 a4 = __builtin_amdgcn_mfma_f32_16x16x32_bf16(A1t[4], B1f, z, 0, 0, 0);
        a4 = __builtin_amdgcn_mfma_f32_16x16x32_bf16(A2t[4], B2f, a4, 0, 0, 0);
        if (sub == 0 && cb < 2)
            *(float4*)&pd2_s[wb][cb][127][0] = make_float4(a4[0], a4[1], a4[2], a4[3]);
    }

    // ---- d2 recurrence: 2 lanes per wave, depth-4 register prefetch (wave-local) ----
    if (l < 2) {
        const float w0 = d2_Whh[0], w1 = d2_Whh[1], w2 = d2_Whh[2], w3 = d2_Whh[3];
        float4 dbuf[4];
        #pragma unroll
        for (int j = 0; j < 4; ++j) dbuf[j] = *(const float4*)&pd2_s[wb][l][j][0];
        float h2 = 0.f, c2 = 0.f;
        #pragma unroll
        for (int ts = 0; ts < 128; ++ts) {
            float4 g4 = dbuf[ts & 3];
            if (ts + 4 < 128) dbuf[ts & 3] = *(const float4*)&pd2_s[wb][l][ts + 4][0];
            float gi = fmaf(h2, w0, g4.x);
            float gf = fmaf(h2, w1, g4.y);
            float gg = fmaf(h2, w2, g4.z);
            float go = fmaf(h2, w3, g4.w);
            c2 = fmaf(sigm(gf), c2, sigm(gi) * tanh_(gg));
            h2 = sigm(go) * tanh_(c2);
            d2h_s[wb][l][ts] = h2;
        }
    }

    // ---- fc1 (128->32) + fc2 (32->32): wave-local, lane -> (batch l>>5, out l&31) ----
    {
        const int cbb = l >> 5, o = l & 31;
        float acc = fc1_b[o];
        const float4* wp = (const float4*)(fc1_W + (size_t)o * 128);
        const float4* fp = (const float4*)&d2h_s[wb][cbb][0];
        #pragma unroll
        for (int k4 = 0; k4 < 32; ++k4) {
            float4 f = fp[k4], vv = wp[k4];
            acc = fmaf(f.x, vv.x, acc); acc = fmaf(f.y, vv.y, acc);
            acc = fmaf(f.z, vv.z, acc); acc = fmaf(f.w, vv.w, acc);
        }
        mid_s[wb][cbb][o] = acc;
        float o2 = fc2_b[o];
        const float4* w2p = (const float4*)(fc2_W + (size_t)o * 32);
        const float4* mp = (const float4*)&mid_s[wb][cbb][0];
        #pragma unroll
        for (int k4 = 0; k4 < 8; ++k4) {
            float4 m = mp[k4], vv = w2p[k4];
            o2 = fmaf(m.x, vv.x, o2); o2 = fmaf(m.y, vv.y, o2);
            o2 = fmaf(m.z, vv.z, o2); o2 = fmaf(m.w, vv.w, o2);
        }
        out[(bBase + 2 * wb + cbb) * 32 + o] = o2;
    }
}

extern "C" void kernel_launch(void* const* d_in, const int* in_sizes, int n_in,
                              void* d_out, int out_size, void* d_ws, size_t ws_size,
                              hipStream_t stream) {
    const float* x      = (const float*)d_in[0];
    const float* e1_Wih = (const float*)d_in[1];
    const float* e1_Whh = (const float*)d_in[2];
    const float* e1_b   = (const float*)d_in[3];
    const float* e2_Wih = (const float*)d_in[4];
    const float* e2_Whh = (const float*)d_in[5];
    const float* e2_b   = (const float*)d_in[6];
    const float* d1_Wih = (const float*)d_in[7];
    const float* d1_Whh = (const float*)d_in[8];
    const float* d1_b   = (const float*)d_in[9];
    const float* d2_Wih = (const float*)d_in[10];
    const float* d2_Whh = (const float*)d_in[11];
    const float* d2_b   = (const float*)d_in[12];
    const float* fc1_W  = (const float*)d_in[13];
    const float* fc1_b  = (const float*)d_in[14];
    const float* fc2_W  = (const float*)d_in[15];
    const float* fc2_b  = (const float*)d_in[16];
    float* out = (float*)d_out;

    float* dec_in = (float*)d_ws;       // [128][4096]

    hipLaunchKernelGGL(k1_enc, dim3(256), dim3(1024), 0, stream,
                       x, e1_Wih, e1_Whh, e1_b, e2_Wih, e2_b, e2_Whh, dec_in);
    hipLaunchKernelGGL(k3_dec, dim3(256), dim3(512), 0, stream,
                       dec_in, d1_Wih, d1_Whh, d1_b, d2_Wih, d2_b, d2_Whh,
                       fc1_W, fc1_b, fc2_W, fc2_b, out);
}

// Round 13
// 188.126 us; speedup vs baseline: 1.2773x; 1.2773x over previous
//
#include <hip/hip_runtime.h>
#include <hip/hip_bf16.h>

typedef __attribute__((ext_vector_type(8))) short bf16x8;
typedef __attribute__((ext_vector_type(4))) float f32x4;

__device__ __forceinline__ float sigm(float x) {
    return __builtin_amdgcn_rcpf(1.0f + __expf(-x));
}
__device__ __forceinline__ float tanh_(float x) {
    float e = __expf(2.0f * x);
    return 1.0f - 2.0f * __builtin_amdgcn_rcpf(e + 1.0f);
}
__device__ __forceinline__ ushort f2bf(float f) {   // RNE float->bf16
    uint u = __float_as_uint(f);
    u = u + 0x7FFFu + ((u >> 16) & 1u);
    return (ushort)(u >> 16);
}
__device__ __forceinline__ float bf2f(ushort s) { return __uint_as_float(((uint)s) << 16); }

// ============ K1: e1 LSTM via MFMA, swapped operands, 16 waves x 1 tile (R10, frozen) ============
__global__ __launch_bounds__(1024) __attribute__((amdgpu_waves_per_eu(4, 4)))
void k1_enc(
    const float* __restrict__ x,
    const float* __restrict__ e1_Wih, const float* __restrict__ e1_Whh, const float* __restrict__ e1_b,
    const float* __restrict__ e2_Wih, const float* __restrict__ e2_b,
    const float* __restrict__ e2_Whh,
    float* __restrict__ dec_in)   // [ts][4096]
{
    __shared__ float x_s[16 * 772];
    __shared__ __align__(16) ushort h_hi[2][8][16][8];
    __shared__ __align__(16) ushort h_lo[2][8][16][8];
    __shared__ __align__(16) ushort x2_s[2][4][16][8];
    __shared__ __align__(16) float pe2_s[96 * 64];

    const int t = threadIdx.x;
    const int bBase = blockIdx.x * 16;
    const int wv = t >> 6, l = t & 63;
    const int row = l & 15, sub = l >> 4;

    for (int bb = 0; bb < 16; ++bb)
        for (int i = t; i < 768; i += 1024)
            x_s[bb * 772 + i] = x[(size_t)(bBase + bb) * 768 + i];

    auto loadW = [&](const float* rowbase, int k0, bool valid, bf16x8& hi8, bf16x8& lo8) {
        float f[8];
        if (valid) {
            float4 v0 = ((const float4*)(rowbase + k0))[0];
            float4 v1 = ((const float4*)(rowbase + k0))[1];
            f[0]=v0.x; f[1]=v0.y; f[2]=v0.z; f[3]=v0.w;
            f[4]=v1.x; f[5]=v1.y; f[6]=v1.z; f[7]=v1.w;
        } else {
            #pragma unroll
            for (int j = 0; j < 8; ++j) f[j] = 0.f;
        }
        #pragma unroll
        for (int j = 0; j < 8; ++j) {
            ushort h = f2bf(f[j]);
            hi8[j] = (short)h;
            lo8[j] = (short)f2bf(f[j] - bf2f(h));
        }
    };
    auto loadA = [&](int T, bool isE2, bf16x8& Ah0, bf16x8& Ah1, bf16x8& Al0, bf16x8& Al1, bf16x8& A2) {
        const int gate = row & 3, uq = row >> 2;
        const bool valid = !isE2 || (uq == 0);
        const int wr = isE2 ? gate : gate * 64 + T * 4 + uq;
        const float* rp = isE2 ? (e2_Wih + (size_t)wr * 64) : (e1_Whh + (size_t)wr * 64);
        loadW(rp, sub * 8,      valid, Ah0, Al0);
        loadW(rp, 32 + sub * 8, valid, Ah1, Al1);
        #pragma unroll
        for (int j = 0; j < 8; ++j) A2[j] = 0;
        if (valid) {
            if (!isE2) {
                if (sub < 3) {
                    const float* wihr = e1_Wih + (size_t)wr * 8;
                    #pragma unroll
                    for (int j = 0; j < 8; ++j) {
                        float f = wihr[j];
                        ushort hh = f2bf(f);
                        A2[j] = (sub < 2) ? (short)hh : (short)f2bf(f - bf2f(hh));
                    }
                } else {
                    float bb = e1_b[wr];
                    ushort hh = f2bf(bb);
                    A2[0] = (short)hh; A2[1] = (short)f2bf(bb - bf2f(hh));
                }
            } else if (sub == 3) {
                float bb = e2_b[wr];
                ushort hh = f2bf(bb);
                A2[0] = (short)hh; A2[1] = (short)f2bf(bb - bf2f(hh));
            }
        }
    };

    bf16x8 A0h0, A0h1, A0l0, A0l1, A0x;
    bf16x8 A2h0, A2h1, A2l0, A2l1, A2x;
    loadA(wv, false, A0h0, A0h1, A0l0, A0l1, A0x);
    if (wv == 15) loadA(0, true, A2h0, A2h1, A2l0, A2l1, A2x);

    __syncthreads();

    if (t < 1024) { ((ushort*)h_hi[0])[t] = 0; ((ushort*)h_lo[0])[t] = 0; }
    if (t < 384) {
        int sb = t >> 7, b = (t >> 3) & 15, j = t & 7;
        float xv = x_s[b * 772 + j];
        ushort hi = f2bf(xv);
        x2_s[0][sb][b][j] = (sb == 1) ? f2bf(xv - bf2f(hi)) : hi;
        x2_s[1][sb][b][j] = 0;
    } else if (t < 512) {
        int b = (t >> 3) & 15, j = t & 7;
        ushort v = (j < 2) ? (ushort)0x3F80 : (ushort)0;
        x2_s[0][3][b][j] = v;
        x2_s[1][3][b][j] = v;
    }

    const int cb = l & 15;
    const int u0_ = wv * 4 + sub;
    float c0r = 0.f;
    __syncthreads();

    #pragma unroll 1
    for (int ts = 0; ts < 96; ++ts) {
        const int p = ts & 1, pn = p ^ 1;

        bf16x8 Bh0 = *(const bf16x8*)&h_hi[p][sub][cb][0];
        bf16x8 Bh1 = *(const bf16x8*)&h_hi[p][4 + sub][cb][0];
        bf16x8 Bl0 = *(const bf16x8*)&h_lo[p][sub][cb][0];
        bf16x8 Bl1 = *(const bf16x8*)&h_lo[p][4 + sub][cb][0];
        bf16x8 Bx  = *(const bf16x8*)&x2_s[p][sub][cb][0];

        f32x4 u0 = {0.f,0.f,0.f,0.f}, v0 = {0.f,0.f,0.f,0.f};
        u0 = __builtin_amdgcn_mfma_f32_16x16x32_bf16(A0h0, Bh0, u0, 0, 0, 0);
        u0 = __builtin_amdgcn_mfma_f32_16x16x32_bf16(A0l0, Bh0, u0, 0, 0, 0);
        u0 = __builtin_amdgcn_mfma_f32_16x16x32_bf16(A0h0, Bl0, u0, 0, 0, 0);
        v0 = __builtin_amdgcn_mfma_f32_16x16x32_bf16(A0h1, Bh1, v0, 0, 0, 0);
        v0 = __builtin_amdgcn_mfma_f32_16x16x32_bf16(A0l1, Bh1, v0, 0, 0, 0);
        v0 = __builtin_amdgcn_mfma_f32_16x16x32_bf16(A0h1, Bl1, v0, 0, 0, 0);
        v0 = __builtin_amdgcn_mfma_f32_16x16x32_bf16(A0x,  Bx,  v0, 0, 0, 0);

        if (wv == 15) {
            f32x4 u2 = {0.f,0.f,0.f,0.f}, v2 = {0.f,0.f,0.f,0.f};
            u2 = __builtin_amdgcn_mfma_f32_16x16x32_bf16(A2h0, Bh0, u2, 0, 0, 0);
            u2 = __builtin_amdgcn_mfma_f32_16x16x32_bf16(A2l0, Bh0, u2, 0, 0, 0);
            u2 = __builtin_amdgcn_mfma_f32_16x16x32_bf16(A2h0, Bl0, u2, 0, 0, 0);
            v2 = __builtin_amdgcn_mfma_f32_16x16x32_bf16(A2h1, Bh1, v2, 0, 0, 0);
            v2 = __builtin_amdgcn_mfma_f32_16x16x32_bf16(A2l1, Bh1, v2, 0, 0, 0);
            v2 = __builtin_amdgcn_mfma_f32_16x16x32_bf16(A2h1, Bl1, v2, 0, 0, 0);
            v2 = __builtin_amdgcn_mfma_f32_16x16x32_bf16(A2x,  Bx,  v2, 0, 0, 0);
            if (ts > 0 && sub == 0) {
                f32x4 acc2 = u2 + v2;
                #pragma unroll
                for (int i = 0; i < 4; ++i)
                    pe2_s[(ts - 1) * 64 + i * 16 + cb] = acc2[i];
            }
        }

        {
            f32x4 acc = u0 + v0;
            c0r = fmaf(sigm(acc[1]), c0r, sigm(acc[0]) * tanh_(acc[2]));
            float hv = sigm(acc[3]) * tanh_(c0r);
            ushort hh = f2bf(hv);
            h_hi[pn][u0_ >> 3][cb][u0_ & 7] = hh;
            h_lo[pn][u0_ >> 3][cb][u0_ & 7] = f2bf(hv - bf2f(hh));
        }

        if (ts < 95 && t < 384) {
            int sb = t >> 7, b = (t >> 3) & 15, j = t & 7;
            float xv = x_s[b * 772 + (ts + 1) * 8 + j];
            ushort hi = f2bf(xv);
            x2_s[pn][sb][b][j] = (sb == 1) ? f2bf(xv - bf2f(hi)) : hi;
        }
        __syncthreads();
    }

    if (wv == 15) {
        bf16x8 Bh0 = *(const bf16x8*)&h_hi[0][sub][cb][0];
        bf16x8 Bh1 = *(const bf16x8*)&h_hi[0][4 + sub][cb][0];
        bf16x8 Bl0 = *(const bf16x8*)&h_lo[0][sub][cb][0];
        bf16x8 Bl1 = *(const bf16x8*)&h_lo[0][4 + sub][cb][0];
        bf16x8 Bx  = *(const bf16x8*)&x2_s[0][sub][cb][0];
        f32x4 u2 = {0.f,0.f,0.f,0.f}, v2 = {0.f,0.f,0.f,0.f};
        u2 = __builtin_amdgcn_mfma_f32_16x16x32_bf16(A2h0, Bh0, u2, 0, 0, 0);
        u2 = __builtin_amdgcn_mfma_f32_16x16x32_bf16(A2l0, Bh0, u2, 0, 0, 0);
        u2 = __builtin_amdgcn_mfma_f32_16x16x32_bf16(A2h0, Bl0, u2, 0, 0, 0);
        v2 = __builtin_amdgcn_mfma_f32_16x16x32_bf16(A2h1, Bh1, v2, 0, 0, 0);
        v2 = __builtin_amdgcn_mfma_f32_16x16x32_bf16(A2l1, Bh1, v2, 0, 0, 0);
        v2 = __builtin_amdgcn_mfma_f32_16x16x32_bf16(A2h1, Bl1, v2, 0, 0, 0);
        v2 = __builtin_amdgcn_mfma_f32_16x16x32_bf16(A2x,  Bx,  v2, 0, 0, 0);
        if (sub == 0) {
            f32x4 acc2 = u2 + v2;
            #pragma unroll
            for (int i = 0; i < 4; ++i)
                pe2_s[95 * 64 + i * 16 + cb] = acc2[i];
        }
    }
    __syncthreads();

    if (wv == 0 && l < 16) {
        const float w0 = e2_Whh[0], w1 = e2_Whh[1], w2 = e2_Whh[2], w3 = e2_Whh[3];
        float ni = pe2_s[l], nf = pe2_s[16 + l], ng = pe2_s[32 + l], no = pe2_s[48 + l];
        float h = 0.f, c = 0.f;
        #pragma unroll 1
        for (int ts = 0; ts < 96; ++ts) {
            float gi = ni, gf = nf, gg2 = ng, go = no;
            if (ts < 95) {
                int b2 = (ts + 1) * 64;
                ni = pe2_s[b2 + l]; nf = pe2_s[b2 + 16 + l];
                ng = pe2_s[b2 + 32 + l]; no = pe2_s[b2 + 48 + l];
            }
            gi = fmaf(h, w0, gi);
            gf = fmaf(h, w1, gf);
            gg2 = fmaf(h, w2, gg2);
            go = fmaf(h, w3, go);
            c = fmaf(sigm(gf), c, sigm(gi) * tanh_(gg2));
            h = sigm(go) * tanh_(c);
            dec_in[(size_t)ts * 4096 + bBase + l] = fmaxf(h, 0.f);
        }
    }
    if (wv >= 1 && wv <= 8) {
        int i = (wv - 1) * 64 + l;
        int B = i >> 5, j = i & 31;
        dec_in[(size_t)(96 + j) * 4096 + bBase + B] = x_s[B * 772 + (64 + j) * 8];
    }
}

// ============ K3 v3: decoder via MFMA, ONE WAVE = 16 BATCHES, zero barriers ============
// 64 threads (1 wave), grid 256 -> 1 block/CU, fully wave-local.
// Identical math to R11's k3 v2 (validated), but B columns = 16 DISTINCT batches
// (R11 served only 2 real batches/wave -> all cell VALU was 8x-replicated waste;
// VALUBusy 62%, 157us). Lane (cb=l&15, sub=l>>4): tile T gives gates i,f,g,o of
// (batch cb, unit 4*sub+T) -> 4 real cells/lane. h in LDS h_s[batch][40]
// (hi 0-15, lo 16-31; pad 40 -> 2-way banks). d2-xg fused (tile 4, sub==0 lanes
// store per-batch float4). d2 recurrence: 16 lanes; fc: lane=(half,o), 8 batches.
__global__ __launch_bounds__(64) __attribute__((amdgpu_waves_per_eu(2, 2)))
void k3_dec(
    const float* __restrict__ dec_in,
    const float* __restrict__ d1_Wih, const float* __restrict__ d1_Whh, const float* __restrict__ d1_b,
    const float* __restrict__ d2_Wih, const float* __restrict__ d2_b,
    const float* __restrict__ d2_Whh,
    const float* __restrict__ fc1_W, const float* __restrict__ fc1_b,
    const float* __restrict__ fc2_W, const float* __restrict__ fc2_b,
    float* __restrict__ out)
{
    __shared__ float din_s[16][132];                    // 8.4 KB
    __shared__ __align__(16) ushort h_s[16][40];        // hi[0-15] | lo[16-31], pad 40
    __shared__ __align__(16) float pd2_s[16][129][4];   // 33 KB, stride 129*4 -> 2-way
    __shared__ float d2h_s[16][132];                    // 8.4 KB
    __shared__ float mid_s[16][36];                     // 2.3 KB

    const int l = threadIdx.x;
    const int cb = l & 15, sub = l >> 4;
    const size_t bBase = (size_t)blockIdx.x * 16;

    // stage dec_in [ts][4096] -> din_s[b][ts]
    for (int i = l; i < 2048; i += 64) {
        int ts = i >> 4, bb = i & 15;
        din_s[bb][ts] = dec_in[(size_t)ts * 4096 + bBase + bb];
    }

    // ---- A fragments (loop-invariant, VGPR-resident) — identical to R11 ----
    bf16x8 A1t[5], A2t[5];
    {
        const int r = l & 15, g = r & 3, ul = r >> 2;
        #pragma unroll
        for (int T = 0; T < 4; ++T) {
            const int grow = g * 16 + 4 * ul + T;
            const float* wr = d1_Whh + grow * 16;
            float wih = d1_Wih[grow], bb = d1_b[grow];
            ushort wih_hi = f2bf(wih), wih_lo = f2bf(wih - bf2f(wih_hi));
            ushort b_hi = f2bf(bb),  b_lo  = f2bf(bb - bf2f(b_hi));
            bf16x8 a1, a2;
            #pragma unroll
            for (int j = 0; j < 8; ++j) {
                int k = sub * 8 + j;
                float w = wr[k & 15];
                ushort whi = f2bf(w);
                a1[j] = (short)whi;
                if (k < 16) a2[j] = (short)f2bf(w - bf2f(whi));
                else {
                    int kk = k - 16;
                    ushort v = (kk == 0) ? wih_hi : (kk == 1) ? wih_hi :
                               (kk == 2) ? b_hi   : (kk == 3) ? b_lo   :
                               (kk == 4) ? wih_lo : (ushort)0;
                    a2[j] = (short)v;
                }
            }
            A1t[T] = a1; A2t[T] = a2;
        }
        {   // d2 tile (rows 0-3 = d2 gates)
            const bool valid = r < 4;
            const float* wr = d2_Wih + (size_t)(r & 3) * 16;
            float bb2 = valid ? d2_b[r & 3] : 0.f;
            ushort b_hi = f2bf(bb2), b_lo = f2bf(bb2 - bf2f(b_hi));
            bf16x8 a1, a2;
            #pragma unroll
            for (int j = 0; j < 8; ++j) {
                int k = sub * 8 + j;
                float w = valid ? wr[k & 15] : 0.f;
                ushort whi = f2bf(w);
                a1[j] = (short)whi;
                if (k < 16) a2[j] = (short)f2bf(w - bf2f(whi));
                else {
                    int kk = k - 16;
                    ushort v = (kk == 2) ? b_hi : (kk == 3) ? b_lo : (ushort)0;
                    a2[j] = valid ? (short)v : (short)0;
                }
            }
            A1t[4] = a1; A2t[4] = a2;
        }
    }

    // init h = 0 (wave-local: 16*40 = 640 ushorts)
    for (int i = l; i < 640; i += 64) ((ushort*)h_s)[i] = 0;

    bf16x8 zero8;
    #pragma unroll
    for (int j = 0; j < 8; ++j) zero8[j] = 0;

    float c_st[4] = {0.f, 0.f, 0.f, 0.f};

    // ================= d1 + fused d2-xg: 128 steps, NO barriers (1 wave) =================
    #pragma unroll 1
    for (int ts = 0; ts < 128; ++ts) {
        bf16x8 B1 = *(const bf16x8*)&h_s[cb][sub * 8];
        float xv = din_s[cb][ts];
        ushort xhi = f2bf(xv), xlo = f2bf(xv - bf2f(xhi));
        bf16x8 xb = zero8;
        xb[0] = (short)xhi; xb[1] = (short)xlo;
        xb[2] = (short)0x3F80; xb[3] = (short)0x3F80; xb[4] = (short)xhi;
        bf16x8 B2 = (sub < 2) ? B1 : (sub == 2) ? xb : zero8;

        f32x4 z = {0.f, 0.f, 0.f, 0.f};
        f32x4 a0 = __builtin_amdgcn_mfma_f32_16x16x32_bf16(A1t[0], B1, z, 0, 0, 0);
        a0 = __builtin_amdgcn_mfma_f32_16x16x32_bf16(A2t[0], B2, a0, 0, 0, 0);
        f32x4 a1 = __builtin_amdgcn_mfma_f32_16x16x32_bf16(A1t[1], B1, z, 0, 0, 0);
        a1 = __builtin_amdgcn_mfma_f32_16x16x32_bf16(A2t[1], B2, a1, 0, 0, 0);
        f32x4 a2 = __builtin_amdgcn_mfma_f32_16x16x32_bf16(A1t[2], B1, z, 0, 0, 0);
        a2 = __builtin_amdgcn_mfma_f32_16x16x32_bf16(A2t[2], B2, a2, 0, 0, 0);
        f32x4 a3 = __builtin_amdgcn_mfma_f32_16x16x32_bf16(A1t[3], B1, z, 0, 0, 0);
        a3 = __builtin_amdgcn_mfma_f32_16x16x32_bf16(A2t[3], B2, a3, 0, 0, 0);
        f32x4 a4 = __builtin_amdgcn_mfma_f32_16x16x32_bf16(A1t[4], B1, z, 0, 0, 0);
        a4 = __builtin_amdgcn_mfma_f32_16x16x32_bf16(A2t[4], B2, a4, 0, 0, 0);

        if (ts > 0 && sub == 0)   // d2-xg from h entering this step, batch cb
            *(float4*)&pd2_s[cb][ts - 1][0] = make_float4(a4[0], a4[1], a4[2], a4[3]);

        float hn[4];
        {
            c_st[0] = fmaf(sigm(a0[1]), c_st[0], sigm(a0[0]) * tanh_(a0[2]));
            hn[0] = sigm(a0[3]) * tanh_(c_st[0]);
            c_st[1] = fmaf(sigm(a1[1]), c_st[1], sigm(a1[0]) * tanh_(a1[2]));
            hn[1] = sigm(a1[3]) * tanh_(c_st[1]);
            c_st[2] = fmaf(sigm(a2[1]), c_st[2], sigm(a2[0]) * tanh_(a2[2]));
            hn[2] = sigm(a2[3]) * tanh_(c_st[2]);
            c_st[3] = fmaf(sigm(a3[1]), c_st[3], sigm(a3[0]) * tanh_(a3[2]));
            hn[3] = sigm(a3[3]) * tanh_(c_st[3]);
        }
        {   // lane's units 4*sub..4*sub+3 of batch cb (contiguous): b64 hi + b64 lo
            uint2 phi, plo;
            phi.x = (uint)f2bf(hn[0]) | ((uint)f2bf(hn[1]) << 16);
            phi.y = (uint)f2bf(hn[2]) | ((uint)f2bf(hn[3]) << 16);
            plo.x = (uint)f2bf(hn[0] - bf2f(f2bf(hn[0]))) | ((uint)f2bf(hn[1] - bf2f(f2bf(hn[1]))) << 16);
            plo.y = (uint)f2bf(hn[2] - bf2f(f2bf(hn[2]))) | ((uint)f2bf(hn[3] - bf2f(f2bf(hn[3]))) << 16);
            *(uint2*)&h_s[cb][4 * sub] = phi;
            *(uint2*)&h_s[cb][16 + 4 * sub] = plo;
        }
    }

    // ---- pd2[127] from final h ----
    {
        bf16x8 B1f = *(const bf16x8*)&h_s[cb][sub * 8];
        bf16x8 onev = zero8; onev[2] = (short)0x3F80; onev[3] = (short)0x3F80;
        bf16x8 B2f = (sub < 2) ? B1f : (sub == 2) ? onev : zero8;
        f32x4 z = {0.f, 0.f, 0.f, 0.f};
        f32x4 a4 = __builtin_amdgcn_mfma_f32_16x16x32_bf16(A1t[4], B1f, z, 0, 0, 0);
        a4 = __builtin_amdgcn_mfma_f32_16x16x32_bf16(A2t[4], B2f, a4, 0, 0, 0);
        if (sub == 0)
            *(float4*)&pd2_s[cb][127][0] = make_float4(a4[0], a4[1], a4[2], a4[3]);
    }

    // ---- d2 recurrence: 16 lanes, one batch each, depth-4 register prefetch ----
    if (l < 16) {
        const float w0 = d2_Whh[0], w1 = d2_Whh[1], w2 = d2_Whh[2], w3 = d2_Whh[3];
        float4 dbuf[4];
        #pragma unroll
        for (int j = 0; j < 4; ++j) dbuf[j] = *(const float4*)&pd2_s[l][j][0];
        float h2 = 0.f, c2 = 0.f;
        #pragma unroll
        for (int ts = 0; ts < 128; ++ts) {
            float4 g4 = dbuf[ts & 3];
            if (ts + 4 < 128) dbuf[ts & 3] = *(const float4*)&pd2_s[l][ts + 4][0];
            float gi = fmaf(h2, w0, g4.x);
            float gf = fmaf(h2, w1, g4.y);
            float gg = fmaf(h2, w2, g4.z);
            float go = fmaf(h2, w3, g4.w);
            c2 = fmaf(sigm(gf), c2, sigm(gi) * tanh_(gg));
            h2 = sigm(go) * tanh_(c2);
            d2h_s[l][ts] = h2;
        }
    }

    // ---- fc1 (128->32) + fc2 (32->32): lane (half=l>>5, o=l&31), 8 batches each ----
    {
        const int half = l >> 5, o = l & 31;
        const float4* wp = (const float4*)(fc1_W + (size_t)o * 128);
        #pragma unroll 1
        for (int it = 0; it < 8; ++it) {
            int bb = 2 * it + half;
            float acc = fc1_b[o];
            const float4* fp = (const float4*)&d2h_s[bb][0];
            #pragma unroll
            for (int k4 = 0; k4 < 32; ++k4) {
                float4 f = fp[k4], vv = wp[k4];
                acc = fmaf(f.x, vv.x, acc); acc = fmaf(f.y, vv.y, acc);
                acc = fmaf(f.z, vv.z, acc); acc = fmaf(f.w, vv.w, acc);
            }
            mid_s[bb][o] = acc;
        }
        const float4* w2p = (const float4*)(fc2_W + (size_t)o * 32);
        #pragma unroll 1
        for (int it = 0; it < 8; ++it) {
            int bb = 2 * it + half;
            float o2 = fc2_b[o];
            const float4* mp = (const float4*)&mid_s[bb][0];
            #pragma unroll
            for (int k4 = 0; k4 < 8; ++k4) {
                float4 m = mp[k4], vv = w2p[k4];
                o2 = fmaf(m.x, vv.x, o2); o2 = fmaf(m.y, vv.y, o2);
                o2 = fmaf(m.z, vv.z, o2); o2 = fmaf(m.w, vv.w, o2);
            }
            out[(bBase + bb) * 32 + o] = o2;
        }
    }
}

extern "C" void kernel_launch(void* const* d_in, const int* in_sizes, int n_in,
                              void* d_out, int out_size, void* d_ws, size_t ws_size,
                              hipStream_t stream) {
    const float* x      = (const float*)d_in[0];
    const float* e1_Wih = (const float*)d_in[1];
    const float* e1_Whh = (const float*)d_in[2];
    const float* e1_b   = (const float*)d_in[3];
    const float* e2_Wih = (const float*)d_in[4];
    const float* e2_Whh = (const float*)d_in[5];
    const float* e2_b   = (const float*)d_in[6];
    const float* d1_Wih = (const float*)d_in[7];
    const float* d1_Whh = (const float*)d_in[8];
    const float* d1_b   = (const float*)d_in[9];
    const float* d2_Wih = (const float*)d_in[10];
    const float* d2_Whh = (const float*)d_in[11];
    const float* d2_b   = (const float*)d_in[12];
    const float* fc1_W  = (const float*)d_in[13];
    const float* fc1_b  = (const float*)d_in[14];
    const float* fc2_W  = (const float*)d_in[15];
    const float* fc2_b  = (const float*)d_in[16];
    float* out = (float*)d_out;

    float* dec_in = (float*)d_ws;       // [128][4096]

    hipLaunchKernelGGL(k1_enc, dim3(256), dim3(1024), 0, stream,
                       x, e1_Wih, e1_Whh, e1_b, e2_Wih, e2_b, e2_Whh, dec_in);
    hipLaunchKernelGGL(k3_dec, dim3(256), dim3(64), 0, stream,
                       dec_in, d1_Wih, d1_Whh, d1_b, d2_Wih, d2_b, d2_Whh,
                       fc1_W, fc1_b, fc2_W, fc2_b, out);
}

// Round 14
// 180.492 us; speedup vs baseline: 1.3314x; 1.0423x over previous
//
#include <hip/hip_runtime.h>
#include <hip/hip_bf16.h>

typedef __attribute__((ext_vector_type(8))) short bf16x8;
typedef __attribute__((ext_vector_type(4))) float f32x4;

__device__ __forceinline__ float sigm(float x) {
    return __builtin_amdgcn_rcpf(1.0f + __expf(-x));
}
__device__ __forceinline__ float tanh_(float x) {
    float e = __expf(2.0f * x);
    return 1.0f - 2.0f * __builtin_amdgcn_rcpf(e + 1.0f);
}
__device__ __forceinline__ ushort f2bf(float f) {   // RNE float->bf16
    uint u = __float_as_uint(f);
    u = u + 0x7FFFu + ((u >> 16) & 1u);
    return (ushort)(u >> 16);
}
__device__ __forceinline__ float bf2f(ushort s) { return __uint_as_float(((uint)s) << 16); }

// ============ K1: e1 LSTM via MFMA, swapped operands, 16 waves x 1 tile (R10, frozen) ============
__global__ __launch_bounds__(1024) __attribute__((amdgpu_waves_per_eu(4, 4)))
void k1_enc(
    const float* __restrict__ x,
    const float* __restrict__ e1_Wih, const float* __restrict__ e1_Whh, const float* __restrict__ e1_b,
    const float* __restrict__ e2_Wih, const float* __restrict__ e2_b,
    const float* __restrict__ e2_Whh,
    float* __restrict__ dec_in)   // [ts][4096]
{
    __shared__ float x_s[16 * 772];
    __shared__ __align__(16) ushort h_hi[2][8][16][8];
    __shared__ __align__(16) ushort h_lo[2][8][16][8];
    __shared__ __align__(16) ushort x2_s[2][4][16][8];
    __shared__ __align__(16) float pe2_s[96 * 64];

    const int t = threadIdx.x;
    const int bBase = blockIdx.x * 16;
    const int wv = t >> 6, l = t & 63;
    const int row = l & 15, sub = l >> 4;

    for (int bb = 0; bb < 16; ++bb)
        for (int i = t; i < 768; i += 1024)
            x_s[bb * 772 + i] = x[(size_t)(bBase + bb) * 768 + i];

    auto loadW = [&](const float* rowbase, int k0, bool valid, bf16x8& hi8, bf16x8& lo8) {
        float f[8];
        if (valid) {
            float4 v0 = ((const float4*)(rowbase + k0))[0];
            float4 v1 = ((const float4*)(rowbase + k0))[1];
            f[0]=v0.x; f[1]=v0.y; f[2]=v0.z; f[3]=v0.w;
            f[4]=v1.x; f[5]=v1.y; f[6]=v1.z; f[7]=v1.w;
        } else {
            #pragma unroll
            for (int j = 0; j < 8; ++j) f[j] = 0.f;
        }
        #pragma unroll
        for (int j = 0; j < 8; ++j) {
            ushort h = f2bf(f[j]);
            hi8[j] = (short)h;
            lo8[j] = (short)f2bf(f[j] - bf2f(h));
        }
    };
    auto loadA = [&](int T, bool isE2, bf16x8& Ah0, bf16x8& Ah1, bf16x8& Al0, bf16x8& Al1, bf16x8& A2) {
        const int gate = row & 3, uq = row >> 2;
        const bool valid = !isE2 || (uq == 0);
        const int wr = isE2 ? gate : gate * 64 + T * 4 + uq;
        const float* rp = isE2 ? (e2_Wih + (size_t)wr * 64) : (e1_Whh + (size_t)wr * 64);
        loadW(rp, sub * 8,      valid, Ah0, Al0);
        loadW(rp, 32 + sub * 8, valid, Ah1, Al1);
        #pragma unroll
        for (int j = 0; j < 8; ++j) A2[j] = 0;
        if (valid) {
            if (!isE2) {
                if (sub < 3) {
                    const float* wihr = e1_Wih + (size_t)wr * 8;
                    #pragma unroll
                    for (int j = 0; j < 8; ++j) {
                        float f = wihr[j];
                        ushort hh = f2bf(f);
                        A2[j] = (sub < 2) ? (short)hh : (short)f2bf(f - bf2f(hh));
                    }
                } else {
                    float bb = e1_b[wr];
                    ushort hh = f2bf(bb);
                    A2[0] = (short)hh; A2[1] = (short)f2bf(bb - bf2f(hh));
                }
            } else if (sub == 3) {
                float bb = e2_b[wr];
                ushort hh = f2bf(bb);
                A2[0] = (short)hh; A2[1] = (short)f2bf(bb - bf2f(hh));
            }
        }
    };

    bf16x8 A0h0, A0h1, A0l0, A0l1, A0x;
    bf16x8 A2h0, A2h1, A2l0, A2l1, A2x;
    loadA(wv, false, A0h0, A0h1, A0l0, A0l1, A0x);
    if (wv == 15) loadA(0, true, A2h0, A2h1, A2l0, A2l1, A2x);

    __syncthreads();

    if (t < 1024) { ((ushort*)h_hi[0])[t] = 0; ((ushort*)h_lo[0])[t] = 0; }
    if (t < 384) {
        int sb = t >> 7, b = (t >> 3) & 15, j = t & 7;
        float xv = x_s[b * 772 + j];
        ushort hi = f2bf(xv);
        x2_s[0][sb][b][j] = (sb == 1) ? f2bf(xv - bf2f(hi)) : hi;
        x2_s[1][sb][b][j] = 0;
    } else if (t < 512) {
        int b = (t >> 3) & 15, j = t & 7;
        ushort v = (j < 2) ? (ushort)0x3F80 : (ushort)0;
        x2_s[0][3][b][j] = v;
        x2_s[1][3][b][j] = v;
    }

    const int cb = l & 15;
    const int u0_ = wv * 4 + sub;
    float c0r = 0.f;
    __syncthreads();

    #pragma unroll 1
    for (int ts = 0; ts < 96; ++ts) {
        const int p = ts & 1, pn = p ^ 1;

        bf16x8 Bh0 = *(const bf16x8*)&h_hi[p][sub][cb][0];
        bf16x8 Bh1 = *(const bf16x8*)&h_hi[p][4 + sub][cb][0];
        bf16x8 Bl0 = *(const bf16x8*)&h_lo[p][sub][cb][0];
        bf16x8 Bl1 = *(const bf16x8*)&h_lo[p][4 + sub][cb][0];
        bf16x8 Bx  = *(const bf16x8*)&x2_s[p][sub][cb][0];

        f32x4 u0 = {0.f,0.f,0.f,0.f}, v0 = {0.f,0.f,0.f,0.f};
        u0 = __builtin_amdgcn_mfma_f32_16x16x32_bf16(A0h0, Bh0, u0, 0, 0, 0);
        u0 = __builtin_amdgcn_mfma_f32_16x16x32_bf16(A0l0, Bh0, u0, 0, 0, 0);
        u0 = __builtin_amdgcn_mfma_f32_16x16x32_bf16(A0h0, Bl0, u0, 0, 0, 0);
        v0 = __builtin_amdgcn_mfma_f32_16x16x32_bf16(A0h1, Bh1, v0, 0, 0, 0);
        v0 = __builtin_amdgcn_mfma_f32_16x16x32_bf16(A0l1, Bh1, v0, 0, 0, 0);
        v0 = __builtin_amdgcn_mfma_f32_16x16x32_bf16(A0h1, Bl1, v0, 0, 0, 0);
        v0 = __builtin_amdgcn_mfma_f32_16x16x32_bf16(A0x,  Bx,  v0, 0, 0, 0);

        if (wv == 15) {
            f32x4 u2 = {0.f,0.f,0.f,0.f}, v2 = {0.f,0.f,0.f,0.f};
            u2 = __builtin_amdgcn_mfma_f32_16x16x32_bf16(A2h0, Bh0, u2, 0, 0, 0);
            u2 = __builtin_amdgcn_mfma_f32_16x16x32_bf16(A2l0, Bh0, u2, 0, 0, 0);
            u2 = __builtin_amdgcn_mfma_f32_16x16x32_bf16(A2h0, Bl0, u2, 0, 0, 0);
            v2 = __builtin_amdgcn_mfma_f32_16x16x32_bf16(A2h1, Bh1, v2, 0, 0, 0);
            v2 = __builtin_amdgcn_mfma_f32_16x16x32_bf16(A2l1, Bh1, v2, 0, 0, 0);
            v2 = __builtin_amdgcn_mfma_f32_16x16x32_bf16(A2h1, Bl1, v2, 0, 0, 0);
            v2 = __builtin_amdgcn_mfma_f32_16x16x32_bf16(A2x,  Bx,  v2, 0, 0, 0);
            if (ts > 0 && sub == 0) {
                f32x4 acc2 = u2 + v2;
                #pragma unroll
                for (int i = 0; i < 4; ++i)
                    pe2_s[(ts - 1) * 64 + i * 16 + cb] = acc2[i];
            }
        }

        {
            f32x4 acc = u0 + v0;
            c0r = fmaf(sigm(acc[1]), c0r, sigm(acc[0]) * tanh_(acc[2]));
            float hv = sigm(acc[3]) * tanh_(c0r);
            ushort hh = f2bf(hv);
            h_hi[pn][u0_ >> 3][cb][u0_ & 7] = hh;
            h_lo[pn][u0_ >> 3][cb][u0_ & 7] = f2bf(hv - bf2f(hh));
        }

        if (ts < 95 && t < 384) {
            int sb = t >> 7, b = (t >> 3) & 15, j = t & 7;
            float xv = x_s[b * 772 + (ts + 1) * 8 + j];
            ushort hi = f2bf(xv);
            x2_s[pn][sb][b][j] = (sb == 1) ? f2bf(xv - bf2f(hi)) : hi;
        }
        __syncthreads();
    }

    if (wv == 15) {
        bf16x8 Bh0 = *(const bf16x8*)&h_hi[0][sub][cb][0];
        bf16x8 Bh1 = *(const bf16x8*)&h_hi[0][4 + sub][cb][0];
        bf16x8 Bl0 = *(const bf16x8*)&h_lo[0][sub][cb][0];
        bf16x8 Bl1 = *(const bf16x8*)&h_lo[0][4 + sub][cb][0];
        bf16x8 Bx  = *(const bf16x8*)&x2_s[0][sub][cb][0];
        f32x4 u2 = {0.f,0.f,0.f,0.f}, v2 = {0.f,0.f,0.f,0.f};
        u2 = __builtin_amdgcn_mfma_f32_16x16x32_bf16(A2h0, Bh0, u2, 0, 0, 0);
        u2 = __builtin_amdgcn_mfma_f32_16x16x32_bf16(A2l0, Bh0, u2, 0, 0, 0);
        u2 = __builtin_amdgcn_mfma_f32_16x16x32_bf16(A2h0, Bl0, u2, 0, 0, 0);
        v2 = __builtin_amdgcn_mfma_f32_16x16x32_bf16(A2h1, Bh1, v2, 0, 0, 0);
        v2 = __builtin_amdgcn_mfma_f32_16x16x32_bf16(A2l1, Bh1, v2, 0, 0, 0);
        v2 = __builtin_amdgcn_mfma_f32_16x16x32_bf16(A2h1, Bl1, v2, 0, 0, 0);
        v2 = __builtin_amdgcn_mfma_f32_16x16x32_bf16(A2x,  Bx,  v2, 0, 0, 0);
        if (sub == 0) {
            f32x4 acc2 = u2 + v2;
            #pragma unroll
            for (int i = 0; i < 4; ++i)
                pe2_s[95 * 64 + i * 16 + cb] = acc2[i];
        }
    }
    __syncthreads();

    if (wv == 0 && l < 16) {
        const float w0 = e2_Whh[0], w1 = e2_Whh[1], w2 = e2_Whh[2], w3 = e2_Whh[3];
        float ni = pe2_s[l], nf = pe2_s[16 + l], ng = pe2_s[32 + l], no = pe2_s[48 + l];
        float h = 0.f, c = 0.f;
        #pragma unroll 1
        for (int ts = 0; ts < 96; ++ts) {
            float gi = ni, gf = nf, gg2 = ng, go = no;
            if (ts < 95) {
                int b2 = (ts + 1) * 64;
                ni = pe2_s[b2 + l]; nf = pe2_s[b2 + 16 + l];
                ng = pe2_s[b2 + 32 + l]; no = pe2_s[b2 + 48 + l];
            }
            gi = fmaf(h, w0, gi);
            gf = fmaf(h, w1, gf);
            gg2 = fmaf(h, w2, gg2);
            go = fmaf(h, w3, go);
            c = fmaf(sigm(gf), c, sigm(gi) * tanh_(gg2));
            h = sigm(go) * tanh_(c);
            dec_in[(size_t)ts * 4096 + bBase + l] = fmaxf(h, 0.f);
        }
    }
    if (wv >= 1 && wv <= 8) {
        int i = (wv - 1) * 64 + l;
        int B = i >> 5, j = i & 31;
        dec_in[(size_t)(96 + j) * 4096 + bBase + B] = x_s[B * 772 + (64 + j) * 8];
    }
}

// ============ K3 v4: decoder, fp32 VALU, K-SPLIT lanes (2 waves/SIMD) ============
// 512 threads (8 waves), 16 batches/block, grid 256. Wave w = batches 2w,2w+1.
// Lane = bp*32 + u*2 + kh: batch-in-pair bp, unit u (0-15), K-half kh (0/1).
// Per lane/step: 4 gates x 8 h-FMAs (half of K=16) + x/bias on kh=0; halves
// combined with ONE shfl_xor(p,1) per gate; cell on kh=0 lanes (fp32, trusted
// R6 numerics); fused d2-xg on (kh=0,u<4) lanes (16 FMA from LDS h, R6-style).
// Doubles wave density vs R6 (2/SIMD vs 1) AND halves the per-lane FMA chain.
// Zero barriers after staging: all state wave-local. d2 recurrence (2 lanes/wave,
// depth-4 prefetch) + fc1 + fc2 wave-local.
__global__ __launch_bounds__(512) __attribute__((amdgpu_waves_per_eu(2, 2)))
void k3_dec(
    const float* __restrict__ dec_in,
    const float* __restrict__ d1_Wih, const float* __restrict__ d1_Whh, const float* __restrict__ d1_b,
    const float* __restrict__ d2_Wih, const float* __restrict__ d2_b,
    const float* __restrict__ d2_Whh,
    const float* __restrict__ fc1_W, const float* __restrict__ fc1_b,
    const float* __restrict__ fc2_W, const float* __restrict__ fc2_b,
    float* __restrict__ out)
{
    __shared__ float din_s[16][132];                  // 8.4 KB
    __shared__ __align__(16) float h_f[16][20];       // stride 20 floats -> 16B-aligned halves
    __shared__ __align__(16) float pd2_s[16][130][4]; // 33 KB
    __shared__ float d2h_s[16][132];                  // 8.4 KB
    __shared__ float mid_s[16][36];                   // 2.3 KB

    const int t = threadIdx.x;
    const int w = t >> 6, l = t & 63;
    const int bp = l >> 5, u = (l >> 1) & 15, kh = l & 1;
    const int row = 2 * w + bp;
    const size_t bBase = (size_t)blockIdx.x * 16;

    // stage dec_in [ts][4096] -> din_s[b][ts]
    for (int i = t; i < 2048; i += 512) {
        int ts = i >> 4, bb = i & 15;
        din_s[bb][ts] = dec_in[(size_t)ts * 4096 + bBase + bb];
    }

    // ---- weights: half-rows of Whh for 4 gates; x/bias on kh==0 ----
    float whh_h[4][8], wih_g[4], bg4[4];
    #pragma unroll
    for (int g = 0; g < 4; ++g) {
        const float4* wp = (const float4*)(d1_Whh + (size_t)(g * 16 + u) * 16 + kh * 8);
        float4 v0 = wp[0], v1 = wp[1];
        whh_h[g][0]=v0.x; whh_h[g][1]=v0.y; whh_h[g][2]=v0.z; whh_h[g][3]=v0.w;
        whh_h[g][4]=v1.x; whh_h[g][5]=v1.y; whh_h[g][6]=v1.z; whh_h[g][7]=v1.w;
        wih_g[g] = d1_Wih[g * 16 + u];
        bg4[g]   = d1_b[g * 16 + u];
    }
    float d2w[16];
    {
        const float4* wp = (const float4*)(d2_Wih + (size_t)(u & 3) * 16);
        #pragma unroll
        for (int k4 = 0; k4 < 4; ++k4) {
            float4 v = wp[k4];
            d2w[4*k4+0] = v.x; d2w[4*k4+1] = v.y; d2w[4*k4+2] = v.z; d2w[4*k4+3] = v.w;
        }
    }
    const float d2bias = d2_b[u & 3];

    float c_u = 0.f;                       // cell state (row,u), live on kh==0 lanes
    if (kh == 0) h_f[row][u] = 0.f;        // wave-local init
    __syncthreads();                       // din_s staged by all threads

    // ================= d1 + fused d2-xg: 128 steps, NO barriers =================
    #pragma unroll 1
    for (int ts = 0; ts < 128; ++ts) {
        float xv = din_s[row][ts];
        float p0, p1, p2, p3;
        if (kh == 0) {
            p0 = fmaf(xv, wih_g[0], bg4[0]);
            p1 = fmaf(xv, wih_g[1], bg4[1]);
            p2 = fmaf(xv, wih_g[2], bg4[2]);
            p3 = fmaf(xv, wih_g[3], bg4[3]);
        } else {
            p0 = p1 = p2 = p3 = 0.f;
        }
        if (ts > 0) {
            const float4* hp = (const float4*)&h_f[row][kh * 8];
            float4 a = hp[0], b = hp[1];
            float hv[8] = {a.x, a.y, a.z, a.w, b.x, b.y, b.z, b.w};
            #pragma unroll
            for (int k = 0; k < 8; ++k) {
                p0 = fmaf(hv[k], whh_h[0][k], p0);
                p1 = fmaf(hv[k], whh_h[1][k], p1);
                p2 = fmaf(hv[k], whh_h[2][k], p2);
                p3 = fmaf(hv[k], whh_h[3][k], p3);
            }
        }
        p0 += __shfl_xor(p0, 1);
        p1 += __shfl_xor(p1, 1);
        p2 += __shfl_xor(p2, 1);
        p3 += __shfl_xor(p3, 1);

        if (kh == 0) {
            c_u = fmaf(sigm(p1), c_u, sigm(p0) * tanh_(p2));
            float hnew = sigm(p3) * tanh_(c_u);
            h_f[row][u] = hnew;
        }
        // fused d2-xg from h of THIS step (wave-ordered after the writes above)
        if (kh == 0 && u < 4) {
            const float4* hp2 = (const float4*)&h_f[row][0];
            float4 h0 = hp2[0], h1 = hp2[1], h2 = hp2[2], h3 = hp2[3];
            float a = d2bias;
            a = fmaf(h0.x, d2w[0],  a); a = fmaf(h0.y, d2w[1],  a);
            a = fmaf(h0.z, d2w[2],  a); a = fmaf(h0.w, d2w[3],  a);
            a = fmaf(h1.x, d2w[4],  a); a = fmaf(h1.y, d2w[5],  a);
            a = fmaf(h1.z, d2w[6],  a); a = fmaf(h1.w, d2w[7],  a);
            a = fmaf(h2.x, d2w[8],  a); a = fmaf(h2.y, d2w[9],  a);
            a = fmaf(h2.z, d2w[10], a); a = fmaf(h2.w, d2w[11], a);
            a = fmaf(h3.x, d2w[12], a); a = fmaf(h3.y, d2w[13], a);
            a = fmaf(h3.z, d2w[14], a); a = fmaf(h3.w, d2w[15], a);
            pd2_s[row][ts][u] = a;
        }
    }

    // ---- d2 recurrence: lanes 0 and 32 of each wave (one batch each), depth-4 prefetch ----
    if ((l & 31) == 0) {
        const float w0 = d2_Whh[0], w1 = d2_Whh[1], w2 = d2_Whh[2], w3 = d2_Whh[3];
        float4 dbuf[4];
        #pragma unroll
        for (int j = 0; j < 4; ++j) dbuf[j] = *(const float4*)&pd2_s[row][j][0];
        float h2 = 0.f, c2 = 0.f;
        #pragma unroll
        for (int ts = 0; ts < 128; ++ts) {
            float4 g4 = dbuf[ts & 3];
            if (ts + 4 < 128) dbuf[ts & 3] = *(const float4*)&pd2_s[row][ts + 4][0];
            float gi = fmaf(h2, w0, g4.x);
            float gf = fmaf(h2, w1, g4.y);
            float gg = fmaf(h2, w2, g4.z);
            float go = fmaf(h2, w3, g4.w);
            c2 = fmaf(sigm(gf), c2, sigm(gi) * tanh_(gg));
            h2 = sigm(go) * tanh_(c2);
            d2h_s[row][ts] = h2;
        }
    }

    // ---- fc1 (128->32) + fc2 (32->32): 64 lanes = 2 batches x 32 outs, wave-local ----
    {
        const int o = l & 31, rowf = 2 * w + (l >> 5);
        float acc = fc1_b[o];
        const float4* wp = (const float4*)(fc1_W + (size_t)o * 128);
        const float4* fp = (const float4*)&d2h_s[rowf][0];
        #pragma unroll
        for (int k4 = 0; k4 < 32; ++k4) {
            float4 f = fp[k4], vv = wp[k4];
            acc = fmaf(f.x, vv.x, acc); acc = fmaf(f.y, vv.y, acc);
            acc = fmaf(f.z, vv.z, acc); acc = fmaf(f.w, vv.w, acc);
        }
        mid_s[rowf][o] = acc;
        float o2 = fc2_b[o];
        const float4* w2p = (const float4*)(fc2_W + (size_t)o * 32);
        const float4* mp = (const float4*)&mid_s[rowf][0];
        #pragma unroll
        for (int k4 = 0; k4 < 8; ++k4) {
            float4 m = mp[k4], vv = w2p[k4];
            o2 = fmaf(m.x, vv.x, o2); o2 = fmaf(m.y, vv.y, o2);
            o2 = fmaf(m.z, vv.z, o2); o2 = fmaf(m.w, vv.w, o2);
        }
        out[(bBase + rowf) * 32 + o] = o2;
    }
}

extern "C" void kernel_launch(void* const* d_in, const int* in_sizes, int n_in,
                              void* d_out, int out_size, void* d_ws, size_t ws_size,
                              hipStream_t stream) {
    const float* x      = (const float*)d_in[0];
    const float* e1_Wih = (const float*)d_in[1];
    const float* e1_Whh = (const float*)d_in[2];
    const float* e1_b   = (const float*)d_in[3];
    const float* e2_Wih = (const float*)d_in[4];
    const float* e2_Whh = (const float*)d_in[5];
    const float* e2_b   = (const float*)d_in[6];
    const float* d1_Wih = (const float*)d_in[7];
    const float* d1_Whh = (const float*)d_in[8];
    const float* d1_b   = (const float*)d_in[9];
    const float* d2_Wih = (const float*)d_in[10];
    const float* d2_Whh = (const float*)d_in[11];
    const float* d2_b   = (const float*)d_in[12];
    const float* fc1_W  = (const float*)d_in[13];
    const float* fc1_b  = (const float*)d_in[14];
    const float* fc2_W  = (const float*)d_in[15];
    const float* fc2_b  = (const float*)d_in[16];
    float* out = (float*)d_out;

    float* dec_in = (float*)d_ws;       // [128][4096]

    hipLaunchKernelGGL(k1_enc, dim3(256), dim3(1024), 0, stream,
                       x, e1_Wih, e1_Whh, e1_b, e2_Wih, e2_b, e2_Whh, dec_in);
    hipLaunchKernelGGL(k3_dec, dim3(256), dim3(512), 0, stream,
                       dec_in, d1_Wih, d1_Whh, d1_b, d2_Wih, d2_b, d2_Whh,
                       fc1_W, fc1_b, fc2_W, fc2_b, out);
}

// Round 15
// 150.009 us; speedup vs baseline: 1.6019x; 1.2032x over previous
//
#include <hip/hip_runtime.h>
#include <hip/hip_bf16.h>

typedef __attribute__((ext_vector_type(8))) short bf16x8;
typedef __attribute__((ext_vector_type(4))) float f32x4;

__device__ __forceinline__ float sigm(float x) {
    return __builtin_amdgcn_rcpf(1.0f + __expf(-x));
}
__device__ __forceinline__ float tanh_(float x) {
    float e = __expf(2.0f * x);
    return 1.0f - 2.0f * __builtin_amdgcn_rcpf(e + 1.0f);
}
__device__ __forceinline__ ushort f2bf(float f) {   // RNE float->bf16
    uint u = __float_as_uint(f);
    u = u + 0x7FFFu + ((u >> 16) & 1u);
    return (ushort)(u >> 16);
}
__device__ __forceinline__ float bf2f(ushort s) { return __uint_as_float(((uint)s) << 16); }

// ============ FUSED: e1(MFMA) + e2 + decoder(d1+d2+fc), one kernel, 16 batches/block ============
// Phase 1 = R10 k1_enc verbatim (16 waves x 1 tile, swapped-operand MFMA, fused e2
// xg + recurrence) but dec_in stays in LDS (din_s). Phase 2 = R6 decoder verbatim
// on threads 0-255 (d1 loop is wave-ordered/barrier-free; the 2 cross-section
// barriers are executed by ALL 1024 threads). Fusion removes: the k3 launch, the
// device-wide drain between kernels, and the 4MB dec_in HBM round-trip.
// LDS total ~134KB < 160KB -> 1 block/CU (as before).
__global__ __launch_bounds__(1024) __attribute__((amdgpu_waves_per_eu(4, 4)))
void fused_all(
    const float* __restrict__ x,
    const float* __restrict__ e1_Wih, const float* __restrict__ e1_Whh, const float* __restrict__ e1_b,
    const float* __restrict__ e2_Wih, const float* __restrict__ e2_b,
    const float* __restrict__ e2_Whh,
    const float* __restrict__ d1_Wih, const float* __restrict__ d1_Whh, const float* __restrict__ d1_b,
    const float* __restrict__ d2_Wih, const float* __restrict__ d2_b,
    const float* __restrict__ d2_Whh,
    const float* __restrict__ fc1_W, const float* __restrict__ fc1_b,
    const float* __restrict__ fc2_W, const float* __restrict__ fc2_b,
    float* __restrict__ out)
{
    // phase-1 arrays
    __shared__ float x_s[16 * 772];                      // 49.4 KB
    __shared__ __align__(16) ushort h_hi[2][8][16][8];   // 4 KB
    __shared__ __align__(16) ushort h_lo[2][8][16][8];   // 4 KB
    __shared__ __align__(16) ushort x2_s[2][4][16][8];   // 2 KB
    __shared__ __align__(16) float pe2_s[96 * 64];       // 24 KB
    // bridge + phase-2 arrays
    __shared__ float din_s[16][132];                     // 8.4 KB
    __shared__ float h_lds[16][16];                      // 1 KB
    __shared__ float pd2_s[16 * 516];                    // 33 KB
    __shared__ float d2h_s[16 * 132];                    // 8.4 KB
    __shared__ float mid_s[16 * 36];                     // 2.3 KB

    const int t = threadIdx.x;
    const int bBase = blockIdx.x * 16;
    const int wv = t >> 6, l = t & 63;
    const int row = l & 15, sub = l >> 4;

    // ---- stage x ----
    for (int bb = 0; bb < 16; ++bb)
        for (int i = t; i < 768; i += 1024)
            x_s[bb * 772 + i] = x[(size_t)(bBase + bb) * 768 + i];

    // ---- A fragments (weights, hi/lo bf16) — loop-invariant ----
    auto loadW = [&](const float* rowbase, int k0, bool valid, bf16x8& hi8, bf16x8& lo8) {
        float f[8];
        if (valid) {
            float4 v0 = ((const float4*)(rowbase + k0))[0];
            float4 v1 = ((const float4*)(rowbase + k0))[1];
            f[0]=v0.x; f[1]=v0.y; f[2]=v0.z; f[3]=v0.w;
            f[4]=v1.x; f[5]=v1.y; f[6]=v1.z; f[7]=v1.w;
        } else {
            #pragma unroll
            for (int j = 0; j < 8; ++j) f[j] = 0.f;
        }
        #pragma unroll
        for (int j = 0; j < 8; ++j) {
            ushort h = f2bf(f[j]);
            hi8[j] = (short)h;
            lo8[j] = (short)f2bf(f[j] - bf2f(h));
        }
    };
    auto loadA = [&](int T, bool isE2, bf16x8& Ah0, bf16x8& Ah1, bf16x8& Al0, bf16x8& Al1, bf16x8& A2) {
        const int gate = row & 3, uq = row >> 2;
        const bool valid = !isE2 || (uq == 0);
        const int wr = isE2 ? gate : gate * 64 + T * 4 + uq;
        const float* rp = isE2 ? (e2_Wih + (size_t)wr * 64) : (e1_Whh + (size_t)wr * 64);
        loadW(rp, sub * 8,      valid, Ah0, Al0);
        loadW(rp, 32 + sub * 8, valid, Ah1, Al1);
        #pragma unroll
        for (int j = 0; j < 8; ++j) A2[j] = 0;
        if (valid) {
            if (!isE2) {
                if (sub < 3) {
                    const float* wihr = e1_Wih + (size_t)wr * 8;
                    #pragma unroll
                    for (int j = 0; j < 8; ++j) {
                        float f = wihr[j];
                        ushort hh = f2bf(f);
                        A2[j] = (sub < 2) ? (short)hh : (short)f2bf(f - bf2f(hh));
                    }
                } else {
                    float bb = e1_b[wr];
                    ushort hh = f2bf(bb);
                    A2[0] = (short)hh; A2[1] = (short)f2bf(bb - bf2f(hh));
                }
            } else if (sub == 3) {
                float bb = e2_b[wr];
                ushort hh = f2bf(bb);
                A2[0] = (short)hh; A2[1] = (short)f2bf(bb - bf2f(hh));
            }
        }
    };

    bf16x8 A0h0, A0h1, A0l0, A0l1, A0x;
    bf16x8 A2h0, A2h1, A2l0, A2l1, A2x;
    loadA(wv, false, A0h0, A0h1, A0l0, A0l1, A0x);
    if (wv == 15) loadA(0, true, A2h0, A2h1, A2l0, A2l1, A2x);

    __syncthreads();   // x_s ready

    if (t < 1024) { ((ushort*)h_hi[0])[t] = 0; ((ushort*)h_lo[0])[t] = 0; }
    if (t < 384) {
        int sb = t >> 7, b = (t >> 3) & 15, j = t & 7;
        float xv = x_s[b * 772 + j];
        ushort hi = f2bf(xv);
        x2_s[0][sb][b][j] = (sb == 1) ? f2bf(xv - bf2f(hi)) : hi;
        x2_s[1][sb][b][j] = 0;
    } else if (t < 512) {
        int b = (t >> 3) & 15, j = t & 7;
        ushort v = (j < 2) ? (ushort)0x3F80 : (ushort)0;
        x2_s[0][3][b][j] = v;
        x2_s[1][3][b][j] = v;
    }

    const int cb = l & 15;
    const int u0_ = wv * 4 + sub;
    float c0r = 0.f;
    __syncthreads();

    // =================== e1 main loop (R10, frozen) ===================
    #pragma unroll 1
    for (int ts = 0; ts < 96; ++ts) {
        const int p = ts & 1, pn = p ^ 1;

        bf16x8 Bh0 = *(const bf16x8*)&h_hi[p][sub][cb][0];
        bf16x8 Bh1 = *(const bf16x8*)&h_hi[p][4 + sub][cb][0];
        bf16x8 Bl0 = *(const bf16x8*)&h_lo[p][sub][cb][0];
        bf16x8 Bl1 = *(const bf16x8*)&h_lo[p][4 + sub][cb][0];
        bf16x8 Bx  = *(const bf16x8*)&x2_s[p][sub][cb][0];

        f32x4 u0 = {0.f,0.f,0.f,0.f}, v0 = {0.f,0.f,0.f,0.f};
        u0 = __builtin_amdgcn_mfma_f32_16x16x32_bf16(A0h0, Bh0, u0, 0, 0, 0);
        u0 = __builtin_amdgcn_mfma_f32_16x16x32_bf16(A0l0, Bh0, u0, 0, 0, 0);
        u0 = __builtin_amdgcn_mfma_f32_16x16x32_bf16(A0h0, Bl0, u0, 0, 0, 0);
        v0 = __builtin_amdgcn_mfma_f32_16x16x32_bf16(A0h1, Bh1, v0, 0, 0, 0);
        v0 = __builtin_amdgcn_mfma_f32_16x16x32_bf16(A0l1, Bh1, v0, 0, 0, 0);
        v0 = __builtin_amdgcn_mfma_f32_16x16x32_bf16(A0h1, Bl1, v0, 0, 0, 0);
        v0 = __builtin_amdgcn_mfma_f32_16x16x32_bf16(A0x,  Bx,  v0, 0, 0, 0);

        if (wv == 15) {
            f32x4 u2 = {0.f,0.f,0.f,0.f}, v2 = {0.f,0.f,0.f,0.f};
            u2 = __builtin_amdgcn_mfma_f32_16x16x32_bf16(A2h0, Bh0, u2, 0, 0, 0);
            u2 = __builtin_amdgcn_mfma_f32_16x16x32_bf16(A2l0, Bh0, u2, 0, 0, 0);
            u2 = __builtin_amdgcn_mfma_f32_16x16x32_bf16(A2h0, Bl0, u2, 0, 0, 0);
            v2 = __builtin_amdgcn_mfma_f32_16x16x32_bf16(A2h1, Bh1, v2, 0, 0, 0);
            v2 = __builtin_amdgcn_mfma_f32_16x16x32_bf16(A2l1, Bh1, v2, 0, 0, 0);
            v2 = __builtin_amdgcn_mfma_f32_16x16x32_bf16(A2h1, Bl1, v2, 0, 0, 0);
            v2 = __builtin_amdgcn_mfma_f32_16x16x32_bf16(A2x,  Bx,  v2, 0, 0, 0);
            if (ts > 0 && sub == 0) {
                f32x4 acc2 = u2 + v2;
                #pragma unroll
                for (int i = 0; i < 4; ++i)
                    pe2_s[(ts - 1) * 64 + i * 16 + cb] = acc2[i];
            }
        }

        {
            f32x4 acc = u0 + v0;
            c0r = fmaf(sigm(acc[1]), c0r, sigm(acc[0]) * tanh_(acc[2]));
            float hv = sigm(acc[3]) * tanh_(c0r);
            ushort hh = f2bf(hv);
            h_hi[pn][u0_ >> 3][cb][u0_ & 7] = hh;
            h_lo[pn][u0_ >> 3][cb][u0_ & 7] = f2bf(hv - bf2f(hh));
        }

        if (ts < 95 && t < 384) {
            int sb = t >> 7, b = (t >> 3) & 15, j = t & 7;
            float xv = x_s[b * 772 + (ts + 1) * 8 + j];
            ushort hi = f2bf(xv);
            x2_s[pn][sb][b][j] = (sb == 1) ? f2bf(xv - bf2f(hi)) : hi;
        }
        __syncthreads();
    }

    // ---- pe2[95] from final h (parity 0) ----
    if (wv == 15) {
        bf16x8 Bh0 = *(const bf16x8*)&h_hi[0][sub][cb][0];
        bf16x8 Bh1 = *(const bf16x8*)&h_hi[0][4 + sub][cb][0];
        bf16x8 Bl0 = *(const bf16x8*)&h_lo[0][sub][cb][0];
        bf16x8 Bl1 = *(const bf16x8*)&h_lo[0][4 + sub][cb][0];
        bf16x8 Bx  = *(const bf16x8*)&x2_s[0][sub][cb][0];
        f32x4 u2 = {0.f,0.f,0.f,0.f}, v2 = {0.f,0.f,0.f,0.f};
        u2 = __builtin_amdgcn_mfma_f32_16x16x32_bf16(A2h0, Bh0, u2, 0, 0, 0);
        u2 = __builtin_amdgcn_mfma_f32_16x16x32_bf16(A2l0, Bh0, u2, 0, 0, 0);
        u2 = __builtin_amdgcn_mfma_f32_16x16x32_bf16(A2h0, Bl0, u2, 0, 0, 0);
        v2 = __builtin_amdgcn_mfma_f32_16x16x32_bf16(A2h1, Bh1, v2, 0, 0, 0);
        v2 = __builtin_amdgcn_mfma_f32_16x16x32_bf16(A2l1, Bh1, v2, 0, 0, 0);
        v2 = __builtin_amdgcn_mfma_f32_16x16x32_bf16(A2h1, Bl1, v2, 0, 0, 0);
        v2 = __builtin_amdgcn_mfma_f32_16x16x32_bf16(A2x,  Bx,  v2, 0, 0, 0);
        if (sub == 0) {
            f32x4 acc2 = u2 + v2;
            #pragma unroll
            for (int i = 0; i < 4; ++i)
                pe2_s[95 * 64 + i * 16 + cb] = acc2[i];
        }
    }
    __syncthreads();

    // ---- fused e2 recurrence -> din_s rows 0..95; x_aux -> rows 96..127 ----
    if (wv == 0 && l < 16) {
        const float w0 = e2_Whh[0], w1 = e2_Whh[1], w2 = e2_Whh[2], w3 = e2_Whh[3];
        float ni = pe2_s[l], nf = pe2_s[16 + l], ng = pe2_s[32 + l], no = pe2_s[48 + l];
        float h = 0.f, c = 0.f;
        #pragma unroll 1
        for (int ts = 0; ts < 96; ++ts) {
            float gi = ni, gf = nf, gg2 = ng, go = no;
            if (ts < 95) {
                int b2 = (ts + 1) * 64;
                ni = pe2_s[b2 + l]; nf = pe2_s[b2 + 16 + l];
                ng = pe2_s[b2 + 32 + l]; no = pe2_s[b2 + 48 + l];
            }
            gi = fmaf(h, w0, gi);
            gf = fmaf(h, w1, gf);
            gg2 = fmaf(h, w2, gg2);
            go = fmaf(h, w3, go);
            c = fmaf(sigm(gf), c, sigm(gi) * tanh_(gg2));
            h = sigm(go) * tanh_(c);
            din_s[l][ts] = fmaxf(h, 0.f);
        }
    }
    if (wv >= 1 && wv <= 8) {
        int i = (wv - 1) * 64 + l;
        int B = i >> 5, j = i & 31;
        din_s[B][96 + j] = x_s[B * 772 + (64 + j) * 8];
    }
    __syncthreads();   // din_s ready for decoder

    // =================== Phase 2: R6 decoder on threads 0-255 ===================
    {
        const int dw = t >> 6, dlane = t & 63;       // dw 0..3 used
        const int dq = dlane >> 4, du = dlane & 15;
        const int drow = dw * 4 + dq;                // batch 0..15

        if (t < 256) {
            float wih_g[4], bg[4], whh_g[4][16], d2w[16];
            #pragma unroll
            for (int g = 0; g < 4; ++g) {
                wih_g[g] = d1_Wih[g * 16 + du];
                bg[g]    = d1_b[g * 16 + du];
                const float4* wp = (const float4*)(d1_Whh + (size_t)(g * 16 + du) * 16);
                #pragma unroll
                for (int k4 = 0; k4 < 4; ++k4) {
                    float4 v = wp[k4];
                    whh_g[g][4*k4+0] = v.x; whh_g[g][4*k4+1] = v.y;
                    whh_g[g][4*k4+2] = v.z; whh_g[g][4*k4+3] = v.w;
                }
            }
            {
                const float4* wp = (const float4*)(d2_Wih + (size_t)(du & 3) * 16);
                #pragma unroll
                for (int k4 = 0; k4 < 4; ++k4) {
                    float4 v = wp[k4];
                    d2w[4*k4+0] = v.x; d2w[4*k4+1] = v.y; d2w[4*k4+2] = v.z; d2w[4*k4+3] = v.w;
                }
            }
            const float d2bias = d2_b[du & 3];

            float h = 0.f, c = 0.f;
            float hv[16];
            #pragma unroll 1
            for (int ts = 0; ts < 128; ++ts) {
                float xv = din_s[drow][ts];
                float p0 = fmaf(xv, wih_g[0], bg[0]);
                float p1 = fmaf(xv, wih_g[1], bg[1]);
                float p2 = fmaf(xv, wih_g[2], bg[2]);
                float p3 = fmaf(xv, wih_g[3], bg[3]);
                if (ts > 0) {
                    const float4* hp = (const float4*)&h_lds[drow][0];
                    #pragma unroll
                    for (int k4 = 0; k4 < 4; ++k4) {
                        float4 v = hp[k4];
                        hv[4*k4+0] = v.x; hv[4*k4+1] = v.y; hv[4*k4+2] = v.z; hv[4*k4+3] = v.w;
                    }
                    #pragma unroll
                    for (int k = 0; k < 16; ++k) {
                        p0 = fmaf(hv[k], whh_g[0][k], p0);
                        p1 = fmaf(hv[k], whh_g[1][k], p1);
                        p2 = fmaf(hv[k], whh_g[2][k], p2);
                        p3 = fmaf(hv[k], whh_g[3][k], p3);
                    }
                    if (du < 4) {
                        float a = d2bias;
                        #pragma unroll
                        for (int k = 0; k < 16; ++k) a = fmaf(hv[k], d2w[k], a);
                        pd2_s[drow * 516 + (ts - 1) * 4 + du] = a;
                    }
                }
                c = fmaf(sigm(p1), c, sigm(p0) * tanh_(p2));
                h = sigm(p3) * tanh_(c);
                h_lds[drow][du] = h;
            }
            {
                const float4* hp = (const float4*)&h_lds[drow][0];
                #pragma unroll
                for (int k4 = 0; k4 < 4; ++k4) {
                    float4 v = hp[k4];
                    hv[4*k4+0] = v.x; hv[4*k4+1] = v.y; hv[4*k4+2] = v.z; hv[4*k4+3] = v.w;
                }
                if (du < 4) {
                    float a = d2bias;
                    #pragma unroll
                    for (int k = 0; k < 16; ++k) a = fmaf(hv[k], d2w[k], a);
                    pd2_s[drow * 516 + 127 * 4 + du] = a;
                }
            }
        }
        __syncthreads();

        // ---- d2 recurrence: 16 lanes, depth-4 register prefetch ----
        if (t < 16) {
            const float w0 = d2_Whh[0], w1 = d2_Whh[1], w2 = d2_Whh[2], w3 = d2_Whh[3];
            float4 dbuf[4];
            #pragma unroll
            for (int j = 0; j < 4; ++j) dbuf[j] = *(const float4*)&pd2_s[t * 516 + j * 4];
            float h2 = 0.f, c2 = 0.f;
            #pragma unroll
            for (int ts = 0; ts < 128; ++ts) {
                float4 g4 = dbuf[ts & 3];
                if (ts + 4 < 128) dbuf[ts & 3] = *(const float4*)&pd2_s[t * 516 + (ts + 4) * 4];
                float gi = fmaf(h2, w0, g4.x);
                float gf = fmaf(h2, w1, g4.y);
                float gg = fmaf(h2, w2, g4.z);
                float go = fmaf(h2, w3, g4.w);
                c2 = fmaf(sigm(gf), c2, sigm(gi) * tanh_(gg));
                h2 = sigm(go) * tanh_(c2);
                d2h_s[t * 132 + ts] = h2;
            }
        }
        __syncthreads();

        // ---- fc1 (128->32) ----
        if (t < 256) {
            const int bb = t >> 4, o = t & 15;
            float acc0 = fc1_b[o], acc1 = fc1_b[o + 16];
            const float4* wa = (const float4*)(fc1_W + (size_t)o * 128);
            const float4* wb = (const float4*)(fc1_W + (size_t)(o + 16) * 128);
            const float4* fp = (const float4*)&d2h_s[bb * 132];
            #pragma unroll
            for (int k4 = 0; k4 < 32; ++k4) {
                float4 f = fp[k4], va = wa[k4], vb = wb[k4];
                acc0 = fmaf(f.x, va.x, acc0); acc0 = fmaf(f.y, va.y, acc0);
                acc0 = fmaf(f.z, va.z, acc0); acc0 = fmaf(f.w, va.w, acc0);
                acc1 = fmaf(f.x, vb.x, acc1); acc1 = fmaf(f.y, vb.y, acc1);
                acc1 = fmaf(f.z, vb.z, acc1); acc1 = fmaf(f.w, vb.w, acc1);
            }
            mid_s[bb * 36 + o] = acc0;
            mid_s[bb * 36 + o + 16] = acc1;
        }
        __syncthreads();

        // ---- fc2 (32->32) ----
        if (t < 256) {
            const int bb = t >> 4, o = t & 15;
            float o0 = fc2_b[o], o1 = fc2_b[o + 16];
            const float4* va2 = (const float4*)(fc2_W + (size_t)o * 32);
            const float4* vb2 = (const float4*)(fc2_W + (size_t)(o + 16) * 32);
            const float4* mp = (const float4*)&mid_s[bb * 36];
            #pragma unroll
            for (int k4 = 0; k4 < 8; ++k4) {
                float4 m = mp[k4], va = va2[k4], vb = vb2[k4];
                o0 = fmaf(m.x, va.x, o0); o0 = fmaf(m.y, va.y, o0);
                o0 = fmaf(m.z, va.z, o0); o0 = fmaf(m.w, va.w, o0);
                o1 = fmaf(m.x, vb.x, o1); o1 = fmaf(m.y, vb.y, o1);
                o1 = fmaf(m.z, vb.z, o1); o1 = fmaf(m.w, vb.w, o1);
            }
            out[((size_t)bBase + bb) * 32 + o] = o0;
            out[((size_t)bBase + bb) * 32 + o + 16] = o1;
        }
    }
}

extern "C" void kernel_launch(void* const* d_in, const int* in_sizes, int n_in,
                              void* d_out, int out_size, void* d_ws, size_t ws_size,
                              hipStream_t stream) {
    const float* x      = (const float*)d_in[0];
    const float* e1_Wih = (const float*)d_in[1];
    const float* e1_Whh = (const float*)d_in[2];
    const float* e1_b   = (const float*)d_in[3];
    const float* e2_Wih = (const float*)d_in[4];
    const float* e2_Whh = (const float*)d_in[5];
    const float* e2_b   = (const float*)d_in[6];
    const float* d1_Wih = (const float*)d_in[7];
    const float* d1_Whh = (const float*)d_in[8];
    const float* d1_b   = (const float*)d_in[9];
    const float* d2_Wih = (const float*)d_in[10];
    const float* d2_Whh = (const float*)d_in[11];
    const float* d2_b   = (const float*)d_in[12];
    const float* fc1_W  = (const float*)d_in[13];
    const float* fc1_b  = (const float*)d_in[14];
    const float* fc2_W  = (const float*)d_in[15];
    const float* fc2_b  = (const float*)d_in[16];
    float* out = (float*)d_out;

    hipLaunchKernelGGL(fused_all, dim3(256), dim3(1024), 0, stream,
                       x, e1_Wih, e1_Whh, e1_b, e2_Wih, e2_b, e2_Whh,
                       d1_Wih, d1_Whh, d1_b, d2_Wih, d2_b, d2_Whh,
                       fc1_W, fc1_b, fc2_W, fc2_b, out);
}